// Round 1
// baseline (1330.182 us; speedup 1.0000x reference)
//
#include <hip/hip_runtime.h>

// Problem: 2-layer GCN (GCNConv with analytic self-loops) + mean-pool + FC.
// N=100000 nodes, E=1.6M edges, F=128, H=128, H2=64, B=50 graphs, C=10.
// Strategy: build CSR-by-dst once (atomic count -> scan -> counting sort with
// precomputed edge norms), then gather-only aggregation (no float scatter
// atomics except tiny B*64 pooling). fp32 throughout for exactness.

#define IDX (blockIdx.x * (int)blockDim.x + (int)threadIdx.x)

// ---------------- degree / normalization ----------------
__global__ void count_deg(const int* __restrict__ dst, int* __restrict__ cnt, int E) {
    int e = IDX;
    if (e < E) atomicAdd(&cnt[dst[e]], 1);
}

__global__ void compute_dinv(const int* __restrict__ cnt, float* __restrict__ dinv,
                             float* __restrict__ winv, int n) {
    int i = IDX;
    if (i < n) {
        float d = 1.0f + (float)cnt[i];      // deg includes self-loop
        dinv[i] = 1.0f / sqrtf(d);
        winv[i] = 1.0f / d;                  // self-loop weight
    }
}

// ---------------- exclusive scan over cnt (N=100000, 1024 items/block) ------
__global__ void scan1(const int* __restrict__ cnt, int* __restrict__ rs,
                      int* __restrict__ bsum, int n) {
    __shared__ int lds[256];
    int t = threadIdx.x;
    int base = blockIdx.x * 1024 + t * 4;
    int c0 = 0, c1 = 0, c2 = 0, c3 = 0;
    if (base + 3 < n) {
        int4 v = *(const int4*)&cnt[base];
        c0 = v.x; c1 = v.y; c2 = v.z; c3 = v.w;
    } else {
        if (base     < n) c0 = cnt[base];
        if (base + 1 < n) c1 = cnt[base + 1];
        if (base + 2 < n) c2 = cnt[base + 2];
        if (base + 3 < n) c3 = cnt[base + 3];
    }
    int s = c0 + c1 + c2 + c3;
    lds[t] = s; __syncthreads();
    for (int off = 1; off < 256; off <<= 1) {
        int v = (t >= off) ? lds[t - off] : 0;
        __syncthreads();
        lds[t] += v;
        __syncthreads();
    }
    int incl = lds[t];
    int excl = incl - s;
    if (t == 255) bsum[blockIdx.x] = incl;
    if (base     < n) rs[base]     = excl;
    if (base + 1 < n) rs[base + 1] = excl + c0;
    if (base + 2 < n) rs[base + 2] = excl + c0 + c1;
    if (base + 3 < n) rs[base + 3] = excl + c0 + c1 + c2;
}

__global__ void scan2(int* __restrict__ bsum, int nb) {   // nb <= 128
    __shared__ int lds[128];
    int t = threadIdx.x;
    int v = (t < nb) ? bsum[t] : 0;
    lds[t] = v; __syncthreads();
    for (int off = 1; off < 128; off <<= 1) {
        int u = (t >= off) ? lds[t - off] : 0;
        __syncthreads();
        lds[t] += u;
        __syncthreads();
    }
    if (t < nb) bsum[t] = lds[t] - v;   // exclusive
}

__global__ void scan3(int* __restrict__ rs, const int* __restrict__ bsum, int n, int E) {
    int i = IDX;
    if (i < n) rs[i] += bsum[i >> 10];
    if (i == 0) rs[n] = E;
}

// ---------------- CSR fill (counting sort by dst) ----------------
__global__ void fill_csr(const int* __restrict__ src, const int* __restrict__ dst,
                         const int* __restrict__ rs, int* __restrict__ cursor,
                         const float* __restrict__ dinv,
                         int* __restrict__ csr_src, float* __restrict__ csr_w, int E) {
    int e = IDX;
    if (e < E) {
        int d = dst[e], s = src[e];
        int p = rs[d] + atomicAdd(&cursor[d], 1);
        csr_src[p] = s;
        csr_w[p]   = dinv[s] * dinv[d];
    }
}

// ---------------- fp32 GEMM: Y[nrows x outw] = X[nrows x 128] @ W[128 x outw]
// 64 rows x 64 cols per block, 4x4 per thread, LDS-staged, conflict-free reads.
__global__ __launch_bounds__(256) void gemm_k128(const float* __restrict__ X,
        const float* __restrict__ W, float* __restrict__ Y, int nrows, int outw) {
    __shared__ float ws[128][64];   // ws[k][c]
    __shared__ float xs[128][64];   // xs[k][r]  (transposed stage)
    const int t = threadIdx.x;
    const int row0 = blockIdx.x * 64;
    const int c0 = blockIdx.y * 64;

    #pragma unroll
    for (int i = 0; i < 8; ++i) {          // 128x64 W tile, float4 loads
        int idx = i * 256 + t;
        int k = idx >> 4, cq = idx & 15;
        float4 v = *(const float4*)&W[(size_t)k * outw + c0 + cq * 4];
        ws[k][cq*4+0] = v.x; ws[k][cq*4+1] = v.y; ws[k][cq*4+2] = v.z; ws[k][cq*4+3] = v.w;
    }
    #pragma unroll
    for (int i = 0; i < 8; ++i) {          // 64x128 X tile -> transposed
        int idx = i * 256 + t;
        int r = idx >> 5, kq = idx & 31;
        float4 v = make_float4(0.f, 0.f, 0.f, 0.f);
        if (row0 + r < nrows) v = *(const float4*)&X[(size_t)(row0 + r) * 128 + kq * 4];
        xs[kq*4+0][r] = v.x; xs[kq*4+1][r] = v.y; xs[kq*4+2][r] = v.z; xs[kq*4+3][r] = v.w;
    }
    __syncthreads();

    const int tr = t >> 4;      // 0..15, rows tr, tr+16, tr+32, tr+48
    const int tc = t & 15;      // 0..15, cols tc, tc+16, tc+32, tc+48
    float acc[4][4] = {};
    #pragma unroll 4
    for (int k = 0; k < 128; ++k) {
        float xv[4], wv[4];
        #pragma unroll
        for (int i = 0; i < 4; ++i) xv[i] = xs[k][tr + 16*i];
        #pragma unroll
        for (int j = 0; j < 4; ++j) wv[j] = ws[k][tc + 16*j];
        #pragma unroll
        for (int i = 0; i < 4; ++i)
            #pragma unroll
            for (int j = 0; j < 4; ++j)
                acc[i][j] = fmaf(xv[i], wv[j], acc[i][j]);
    }
    #pragma unroll
    for (int i = 0; i < 4; ++i) {
        int row = row0 + tr + 16*i;
        if (row < nrows) {
            #pragma unroll
            for (int j = 0; j < 4; ++j)
                Y[(size_t)row * outw + c0 + tc + 16*j] = acc[i][j];
        }
    }
}

// ---------------- gather aggregation: out = relu(agg + h*winv + bias) -------
// One wave per node. FW=128: each lane owns feats (2*lane, 2*lane+1) via float2.
// FW=64: lane owns feat lane; optionally fuse mean-pool atomics.
template<int FW, bool POOL>
__global__ __launch_bounds__(256) void aggregate(
        const float* __restrict__ h, const int* __restrict__ rs,
        const int* __restrict__ csr_src, const float* __restrict__ csr_w,
        const float* __restrict__ winv, const float* __restrict__ bias,
        const int* __restrict__ batch, float* __restrict__ pooled,
        float* __restrict__ out, int n) {
    int node = blockIdx.x * 4 + ((int)threadIdx.x >> 6);
    int lane = (int)threadIdx.x & 63;
    if (node >= n) return;
    int b0 = rs[node], b1 = rs[node + 1];

    float a0 = 0.f, a1 = 0.f;
    int e = b0;
    for (; e + 4 <= b1; e += 4) {
        int s0 = csr_src[e], s1 = csr_src[e+1], s2 = csr_src[e+2], s3 = csr_src[e+3];
        float w0 = csr_w[e], w1 = csr_w[e+1], w2 = csr_w[e+2], w3 = csr_w[e+3];
        if (FW == 128) {
            float2 v0 = *(const float2*)&h[(size_t)s0*128 + lane*2];
            float2 v1 = *(const float2*)&h[(size_t)s1*128 + lane*2];
            float2 v2 = *(const float2*)&h[(size_t)s2*128 + lane*2];
            float2 v3 = *(const float2*)&h[(size_t)s3*128 + lane*2];
            a0 += v0.x*w0 + v1.x*w1 + v2.x*w2 + v3.x*w3;
            a1 += v0.y*w0 + v1.y*w1 + v2.y*w2 + v3.y*w3;
        } else {
            float v0 = h[(size_t)s0*64 + lane];
            float v1 = h[(size_t)s1*64 + lane];
            float v2 = h[(size_t)s2*64 + lane];
            float v3 = h[(size_t)s3*64 + lane];
            a0 += v0*w0 + v1*w1 + v2*w2 + v3*w3;
        }
    }
    for (; e < b1; ++e) {
        int s = csr_src[e];
        float w = csr_w[e];
        if (FW == 128) {
            float2 v = *(const float2*)&h[(size_t)s*128 + lane*2];
            a0 += v.x * w; a1 += v.y * w;
        } else {
            a0 += h[(size_t)s*64 + lane] * w;
        }
    }

    float wself = winv[node];
    if (FW == 128) {
        float2 hv = *(const float2*)&h[(size_t)node*128 + lane*2];
        float2 bv = *(const float2*)&bias[lane*2];
        float o0 = fmaxf(a0 + hv.x * wself + bv.x, 0.f);
        float o1 = fmaxf(a1 + hv.y * wself + bv.y, 0.f);
        *(float2*)&out[(size_t)node*128 + lane*2] = make_float2(o0, o1);
    } else {
        float hv = h[(size_t)node*64 + lane];
        float o = fmaxf(a0 + hv * wself + bias[lane], 0.f);
        out[(size_t)node*64 + lane] = o;
        if (POOL) atomicAdd(&pooled[(size_t)batch[node]*64 + lane], o);
    }
}

// ---------------- pooling counts + FC ----------------
__global__ void count_batch(const int* __restrict__ batch, int* __restrict__ cntB, int n) {
    int i = IDX;
    if (i < n) atomicAdd(&cntB[batch[i]], 1);
}

__global__ void fc_kernel(const float* __restrict__ pooled, const int* __restrict__ cntB,
                          const float* __restrict__ Wfc, const float* __restrict__ bfc,
                          float* __restrict__ out) {
    int t = IDX;
    if (t < 50 * 10) {
        int b = t / 10, c = t % 10;
        float inv = 1.0f / fmaxf((float)cntB[b], 1.0f);
        float s = bfc[c];
        #pragma unroll
        for (int f = 0; f < 64; ++f)
            s = fmaf(pooled[b*64 + f] * inv, Wfc[f*10 + c], s);
        out[t] = s;
    }
}

extern "C" void kernel_launch(void* const* d_in, const int* in_sizes, int n_in,
                              void* d_out, int out_size, void* d_ws, size_t ws_size,
                              hipStream_t stream) {
    const float* x     = (const float*)d_in[0];
    const int*   ei    = (const int*)d_in[1];
    const int*   batch = (const int*)d_in[2];
    const float* W1    = (const float*)d_in[3];
    const float* b1    = (const float*)d_in[4];
    const float* W2    = (const float*)d_in[5];
    const float* b2    = (const float*)d_in[6];
    const float* Wfc   = (const float*)d_in[7];
    const float* bfc   = (const float*)d_in[8];
    float* out = (float*)d_out;

    const int n = in_sizes[2];          // 100000
    const int E = in_sizes[1] / 2;      // 1600000
    const int* src = ei;
    const int* dst = ei + E;

    // bump-allocate workspace (256B aligned regions)
    char* p = (char*)d_ws;
    auto alloc = [&](size_t bytes) { char* r = p; p += (bytes + 255) & ~(size_t)255; return r; };
    int*   cnt     = (int*)  alloc((size_t)n * 4);
    int*   cursor  = (int*)  alloc((size_t)n * 4);
    int*   cntB    = (int*)  alloc(50 * 4);
    float* pooled  = (float*)alloc(50 * 64 * 4);
    size_t zbytes  = (size_t)(p - (char*)d_ws);      // zero-init region
    int*   bsum    = (int*)  alloc(128 * 4);
    int*   rs      = (int*)  alloc((size_t)(n + 1) * 4);
    int*   csr_src = (int*)  alloc((size_t)E * 4);
    float* csr_w   = (float*)alloc((size_t)E * 4);
    float* dinv    = (float*)alloc((size_t)n * 4);
    float* winv    = (float*)alloc((size_t)n * 4);
    float* h_raw   = (float*)alloc((size_t)n * 128 * 4);
    float* h_act   = (float*)alloc((size_t)n * 128 * 4);

    hipMemsetAsync(d_ws, 0, zbytes, stream);

    int eb    = (E + 255) / 256;
    int nb256 = (n + 255) / 256;
    int nscan = (n + 1023) / 1024;      // 98 blocks (<=128 for scan2)

    count_deg<<<eb, 256, 0, stream>>>(dst, cnt, E);
    compute_dinv<<<nb256, 256, 0, stream>>>(cnt, dinv, winv, n);
    scan1<<<nscan, 256, 0, stream>>>(cnt, rs, bsum, n);
    scan2<<<1, 128, 0, stream>>>(bsum, nscan);
    scan3<<<nb256, 256, 0, stream>>>(rs, bsum, n, E);
    fill_csr<<<eb, 256, 0, stream>>>(src, dst, rs, cursor, dinv, csr_src, csr_w, E);

    // layer 1: h_raw = x @ W1 ; h_act = relu(agg(h_raw) + h_raw*winv + b1)
    dim3 g1((n + 63) / 64, 2);
    gemm_k128<<<g1, 256, 0, stream>>>(x, W1, h_raw, n, 128);
    int nagg = (n + 3) / 4;
    aggregate<128, false><<<nagg, 256, 0, stream>>>(h_raw, rs, csr_src, csr_w,
                                                    winv, b1, batch, pooled, h_act, n);

    // layer 2: h_raw(:, :64) = h_act @ W2 ; h_act(:, :64) = relu(...) + fused pooling
    dim3 g2((n + 63) / 64, 1);
    gemm_k128<<<g2, 256, 0, stream>>>(h_act, W2, h_raw, n, 64);
    count_batch<<<nb256, 256, 0, stream>>>(batch, cntB, n);
    aggregate<64, true><<<nagg, 256, 0, stream>>>(h_raw, rs, csr_src, csr_w,
                                                  winv, b2, batch, pooled, h_act, n);

    fc_kernel<<<1, 512, 0, stream>>>(pooled, cntB, Wfc, bfc, out);
}

// Round 5
// 704.292 us; speedup vs baseline: 1.8887x; 1.8887x over previous
//
#include <hip/hip_runtime.h>

// Problem: 2-layer GCN (GCNConv with analytic self-loops) + mean-pool + FC.
// N=100000 nodes, E=1.6M edges, F=128, H=128, H2=64, B=50 graphs, C=10.
// Strategy: build CSR-by-dst once (atomic count -> scan -> counting sort with
// precomputed edge norms), then gather-only aggregation (no float scatter
// atomics except tiny B*64 pooling). fp32 throughout for exactness.
// R1: replaced count_batch (100k atomics into 50 sorted counters = 567us of
// pure contention) with 50 binary searches over the sorted batch array.
// R2/R3: resubmit (GPU acquisition timeouts, no data).
// R4: GEMM rework — was LDS-bound (8 ds_read_b32 per 16 FMA) with a 32-way
// bank conflict in the X-transpose staging. Now: xs[r][k] untransposed,
// thread owns 4 consecutive rows x 4 consecutive cols, k unrolled by 4 ->
// 8 ds_read_b128 per 64 FMA (compute-bound), float4 epilogue stores.

#define IDX (blockIdx.x * (int)blockDim.x + (int)threadIdx.x)

// ---------------- degree / normalization ----------------
__global__ void count_deg(const int* __restrict__ dst, int* __restrict__ cnt, int E) {
    int e = IDX;
    if (e < E) atomicAdd(&cnt[dst[e]], 1);
}

__global__ void compute_dinv(const int* __restrict__ cnt, float* __restrict__ dinv,
                             float* __restrict__ winv, int n) {
    int i = IDX;
    if (i < n) {
        float d = 1.0f + (float)cnt[i];      // deg includes self-loop
        dinv[i] = 1.0f / sqrtf(d);
        winv[i] = 1.0f / d;                  // self-loop weight
    }
}

// ---------------- exclusive scan over cnt (N=100000, 1024 items/block) ------
__global__ void scan1(const int* __restrict__ cnt, int* __restrict__ rs,
                      int* __restrict__ bsum, int n) {
    __shared__ int lds[256];
    int t = threadIdx.x;
    int base = blockIdx.x * 1024 + t * 4;
    int c0 = 0, c1 = 0, c2 = 0, c3 = 0;
    if (base + 3 < n) {
        int4 v = *(const int4*)&cnt[base];
        c0 = v.x; c1 = v.y; c2 = v.z; c3 = v.w;
    } else {
        if (base     < n) c0 = cnt[base];
        if (base + 1 < n) c1 = cnt[base + 1];
        if (base + 2 < n) c2 = cnt[base + 2];
        if (base + 3 < n) c3 = cnt[base + 3];
    }
    int s = c0 + c1 + c2 + c3;
    lds[t] = s; __syncthreads();
    for (int off = 1; off < 256; off <<= 1) {
        int v = (t >= off) ? lds[t - off] : 0;
        __syncthreads();
        lds[t] += v;
        __syncthreads();
    }
    int incl = lds[t];
    int excl = incl - s;
    if (t == 255) bsum[blockIdx.x] = incl;
    if (base     < n) rs[base]     = excl;
    if (base + 1 < n) rs[base + 1] = excl + c0;
    if (base + 2 < n) rs[base + 2] = excl + c0 + c1;
    if (base + 3 < n) rs[base + 3] = excl + c0 + c1 + c2;
}

__global__ void scan2(int* __restrict__ bsum, int nb) {   // nb <= 128
    __shared__ int lds[128];
    int t = threadIdx.x;
    int v = (t < nb) ? bsum[t] : 0;
    lds[t] = v; __syncthreads();
    for (int off = 1; off < 128; off <<= 1) {
        int u = (t >= off) ? lds[t - off] : 0;
        __syncthreads();
        lds[t] += u;
        __syncthreads();
    }
    if (t < nb) bsum[t] = lds[t] - v;   // exclusive
}

__global__ void scan3(int* __restrict__ rs, const int* __restrict__ bsum, int n, int E) {
    int i = IDX;
    if (i < n) rs[i] += bsum[i >> 10];
    if (i == 0) rs[n] = E;
}

// ---------------- CSR fill (counting sort by dst) ----------------
__global__ void fill_csr(const int* __restrict__ src, const int* __restrict__ dst,
                         const int* __restrict__ rs, int* __restrict__ cursor,
                         const float* __restrict__ dinv,
                         int* __restrict__ csr_src, float* __restrict__ csr_w, int E) {
    int e = IDX;
    if (e < E) {
        int d = dst[e], s = src[e];
        int p = rs[d] + atomicAdd(&cursor[d], 1);
        csr_src[p] = s;
        csr_w[p]   = dinv[s] * dinv[d];
    }
}

// ---------------- fp32 GEMM: Y[nrows x outw] = X[nrows x 128] @ W[128 x outw]
// 64 rows x 64 cols per block; thread owns 4 consecutive rows x 4 consecutive
// cols; k unrolled by 4 -> all LDS reads are ds_read_b128, conflict-free
// (X reads broadcast within 16-lane groups, W reads 2-way = free).
__global__ __launch_bounds__(256) void gemm_k128(const float* __restrict__ X,
        const float* __restrict__ W, float* __restrict__ Y, int nrows, int outw) {
    __shared__ float ws[128][64];   // ws[k][c]
    __shared__ float xs[64][128];   // xs[r][k]  (same layout as global)
    const int t = threadIdx.x;
    const int row0 = blockIdx.x * 64;
    const int c0 = blockIdx.y * 64;

    #pragma unroll
    for (int i = 0; i < 8; ++i) {          // 128x64 W tile, float4 in+out
        int idx = i * 256 + t;
        int k = idx >> 4, cq = idx & 15;
        float4 v = *(const float4*)&W[(size_t)k * outw + c0 + cq * 4];
        *(float4*)&ws[k][cq * 4] = v;
    }
    #pragma unroll
    for (int i = 0; i < 8; ++i) {          // 64x128 X tile, direct layout
        int idx = i * 256 + t;
        int r = idx >> 5, kq = idx & 31;
        float4 v = make_float4(0.f, 0.f, 0.f, 0.f);
        if (row0 + r < nrows) v = *(const float4*)&X[(size_t)(row0 + r) * 128 + kq * 4];
        *(float4*)&xs[r][kq * 4] = v;
    }
    __syncthreads();

    const int r0  = (t >> 4) * 4;   // rows r0..r0+3
    const int cc0 = (t & 15) * 4;   // cols cc0..cc0+3
    float acc[4][4] = {};
    #pragma unroll 2
    for (int k0 = 0; k0 < 128; k0 += 4) {
        float xv[4][4], wv[4][4];
        #pragma unroll
        for (int i = 0; i < 4; ++i)
            *(float4*)xv[i] = *(const float4*)&xs[r0 + i][k0];
        #pragma unroll
        for (int kk = 0; kk < 4; ++kk)
            *(float4*)wv[kk] = *(const float4*)&ws[k0 + kk][cc0];
        #pragma unroll
        for (int i = 0; i < 4; ++i)
            #pragma unroll
            for (int kk = 0; kk < 4; ++kk)
                #pragma unroll
                for (int j = 0; j < 4; ++j)
                    acc[i][j] = fmaf(xv[i][kk], wv[kk][j], acc[i][j]);
    }
    #pragma unroll
    for (int i = 0; i < 4; ++i) {
        int row = row0 + r0 + i;
        if (row < nrows)
            *(float4*)&Y[(size_t)row * outw + c0 + cc0] = *(const float4*)acc[i];
    }
}

// ---------------- gather aggregation: out = relu(agg + h*winv + bias) -------
// One wave per node. FW=128: each lane owns feats (2*lane, 2*lane+1) via float2.
// FW=64: lane owns feat lane; optionally fuse mean-pool atomics.
template<int FW, bool POOL>
__global__ __launch_bounds__(256) void aggregate(
        const float* __restrict__ h, const int* __restrict__ rs,
        const int* __restrict__ csr_src, const float* __restrict__ csr_w,
        const float* __restrict__ winv, const float* __restrict__ bias,
        const int* __restrict__ batch, float* __restrict__ pooled,
        float* __restrict__ out, int n) {
    int node = blockIdx.x * 4 + ((int)threadIdx.x >> 6);
    int lane = (int)threadIdx.x & 63;
    if (node >= n) return;
    int b0 = rs[node], b1 = rs[node + 1];

    float a0 = 0.f, a1 = 0.f;
    int e = b0;
    for (; e + 4 <= b1; e += 4) {
        int s0 = csr_src[e], s1 = csr_src[e+1], s2 = csr_src[e+2], s3 = csr_src[e+3];
        float w0 = csr_w[e], w1 = csr_w[e+1], w2 = csr_w[e+2], w3 = csr_w[e+3];
        if (FW == 128) {
            float2 v0 = *(const float2*)&h[(size_t)s0*128 + lane*2];
            float2 v1 = *(const float2*)&h[(size_t)s1*128 + lane*2];
            float2 v2 = *(const float2*)&h[(size_t)s2*128 + lane*2];
            float2 v3 = *(const float2*)&h[(size_t)s3*128 + lane*2];
            a0 += v0.x*w0 + v1.x*w1 + v2.x*w2 + v3.x*w3;
            a1 += v0.y*w0 + v1.y*w1 + v2.y*w2 + v3.y*w3;
        } else {
            float v0 = h[(size_t)s0*64 + lane];
            float v1 = h[(size_t)s1*64 + lane];
            float v2 = h[(size_t)s2*64 + lane];
            float v3 = h[(size_t)s3*64 + lane];
            a0 += v0*w0 + v1*w1 + v2*w2 + v3*w3;
        }
    }
    for (; e < b1; ++e) {
        int s = csr_src[e];
        float w = csr_w[e];
        if (FW == 128) {
            float2 v = *(const float2*)&h[(size_t)s*128 + lane*2];
            a0 += v.x * w; a1 += v.y * w;
        } else {
            a0 += h[(size_t)s*64 + lane] * w;
        }
    }

    float wself = winv[node];
    if (FW == 128) {
        float2 hv = *(const float2*)&h[(size_t)node*128 + lane*2];
        float2 bv = *(const float2*)&bias[lane*2];
        float o0 = fmaxf(a0 + hv.x * wself + bv.x, 0.f);
        float o1 = fmaxf(a1 + hv.y * wself + bv.y, 0.f);
        *(float2*)&out[(size_t)node*128 + lane*2] = make_float2(o0, o1);
    } else {
        float hv = h[(size_t)node*64 + lane];
        float o = fmaxf(a0 + hv * wself + bias[lane], 0.f);
        out[(size_t)node*64 + lane] = o;
        if (POOL) atomicAdd(&pooled[(size_t)batch[node]*64 + lane], o);
    }
}

// ---------------- pooling counts (batch is SORTED -> binary search) ---------
__global__ void graph_counts(const int* __restrict__ batch, int* __restrict__ cntB,
                             int n, int B) {
    int b = (int)threadIdx.x;
    if (b < B) {
        int lo = 0, hi = n;                 // lower_bound(b)
        while (lo < hi) { int mid = (lo + hi) >> 1; if (batch[mid] < b) lo = mid + 1; else hi = mid; }
        int start = lo;
        lo = 0; hi = n;                     // upper_bound(b)
        while (lo < hi) { int mid = (lo + hi) >> 1; if (batch[mid] <= b) lo = mid + 1; else hi = mid; }
        cntB[b] = lo - start;
    }
}

__global__ void fc_kernel(const float* __restrict__ pooled, const int* __restrict__ cntB,
                          const float* __restrict__ Wfc, const float* __restrict__ bfc,
                          float* __restrict__ out) {
    int t = IDX;
    if (t < 50 * 10) {
        int b = t / 10, c = t % 10;
        float inv = 1.0f / fmaxf((float)cntB[b], 1.0f);
        float s = bfc[c];
        #pragma unroll
        for (int f = 0; f < 64; ++f)
            s = fmaf(pooled[b*64 + f] * inv, Wfc[f*10 + c], s);
        out[t] = s;
    }
}

extern "C" void kernel_launch(void* const* d_in, const int* in_sizes, int n_in,
                              void* d_out, int out_size, void* d_ws, size_t ws_size,
                              hipStream_t stream) {
    const float* x     = (const float*)d_in[0];
    const int*   ei    = (const int*)d_in[1];
    const int*   batch = (const int*)d_in[2];
    const float* W1    = (const float*)d_in[3];
    const float* b1    = (const float*)d_in[4];
    const float* W2    = (const float*)d_in[5];
    const float* b2    = (const float*)d_in[6];
    const float* Wfc   = (const float*)d_in[7];
    const float* bfc   = (const float*)d_in[8];
    float* out = (float*)d_out;

    const int n = in_sizes[2];          // 100000
    const int E = in_sizes[1] / 2;      // 1600000
    const int* src = ei;
    const int* dst = ei + E;

    // bump-allocate workspace (256B aligned regions)
    char* p = (char*)d_ws;
    auto alloc = [&](size_t bytes) { char* r = p; p += (bytes + 255) & ~(size_t)255; return r; };
    int*   cnt     = (int*)  alloc((size_t)n * 4);
    int*   cursor  = (int*)  alloc((size_t)n * 4);
    float* pooled  = (float*)alloc(50 * 64 * 4);
    size_t zbytes  = (size_t)(p - (char*)d_ws);      // zero-init region
    int*   cntB    = (int*)  alloc(50 * 4);
    int*   bsum    = (int*)  alloc(128 * 4);
    int*   rs      = (int*)  alloc((size_t)(n + 1) * 4);
    int*   csr_src = (int*)  alloc((size_t)E * 4);
    float* csr_w   = (float*)alloc((size_t)E * 4);
    float* dinv    = (float*)alloc((size_t)n * 4);
    float* winv    = (float*)alloc((size_t)n * 4);
    float* h_raw   = (float*)alloc((size_t)n * 128 * 4);
    float* h_act   = (float*)alloc((size_t)n * 128 * 4);

    hipMemsetAsync(d_ws, 0, zbytes, stream);

    int eb    = (E + 255) / 256;
    int nb256 = (n + 255) / 256;
    int nscan = (n + 1023) / 1024;      // 98 blocks (<=128 for scan2)

    count_deg<<<eb, 256, 0, stream>>>(dst, cnt, E);
    compute_dinv<<<nb256, 256, 0, stream>>>(cnt, dinv, winv, n);
    scan1<<<nscan, 256, 0, stream>>>(cnt, rs, bsum, n);
    scan2<<<1, 128, 0, stream>>>(bsum, nscan);
    scan3<<<nb256, 256, 0, stream>>>(rs, bsum, n, E);
    fill_csr<<<eb, 256, 0, stream>>>(src, dst, rs, cursor, dinv, csr_src, csr_w, E);

    // layer 1: h_raw = x @ W1 ; h_act = relu(agg(h_raw) + h_raw*winv + b1)
    dim3 g1((n + 63) / 64, 2);
    gemm_k128<<<g1, 256, 0, stream>>>(x, W1, h_raw, n, 128);
    int nagg = (n + 3) / 4;
    aggregate<128, false><<<nagg, 256, 0, stream>>>(h_raw, rs, csr_src, csr_w,
                                                    winv, b1, batch, pooled, h_act, n);

    // layer 2: h_raw(:, :64) = h_act @ W2 ; h_act(:, :64) = relu(...) + fused pooling
    dim3 g2((n + 63) / 64, 1);
    gemm_k128<<<g2, 256, 0, stream>>>(h_act, W2, h_raw, n, 64);
    graph_counts<<<1, 64, 0, stream>>>(batch, cntB, n, 50);
    aggregate<64, true><<<nagg, 256, 0, stream>>>(h_raw, rs, csr_src, csr_w,
                                                  winv, b2, batch, pooled, h_act, n);

    fc_kernel<<<1, 512, 0, stream>>>(pooled, cntB, Wfc, bfc, out);
}